// Round 1
// baseline (117.969 us; speedup 1.0000x reference)
//
#include <hip/hip_runtime.h>
#include <math.h>

#define POS_WEIGHT 7.0f
#define POSITION_WEIGHT 0.1f
#define NBLOCKS 2048
#define BLOCK 256

// stable softplus: log(1 + e^x)
__device__ __forceinline__ float softplusf(float x) {
    return fmaxf(x, 0.0f) + log1pf(__expf(-fabsf(x)));
}

// stable sigmoid
__device__ __forceinline__ float sigmoidf_(float x) {
    float e = __expf(-fabsf(x));
    float r = e / (1.0f + e);          // value for x < 0
    return (x >= 0.0f) ? (1.0f - r) : r;
}

__global__ __launch_bounds__(BLOCK) void pos_loss_kernel(
    const float* __restrict__ logits,   // [n,2]
    const int*   __restrict__ labels,   // [n]
    const int*   __restrict__ batch,    // [n]
    float* __restrict__ acc,            // [3]: sum(w*nll), sum(w), pos_loss
    int n)
{
    const int nchunks = n >> 2;               // 4 elements per chunk
    float s_wnll = 0.0f, s_w = 0.0f, s_pos = 0.0f;

    const int stride = gridDim.x * blockDim.x;
    for (int c = blockIdx.x * blockDim.x + threadIdx.x; c < nchunks; c += stride) {
        const int base = c << 2;

        // vector loads: 2x float4 = 4 logit rows, int4 labels, int4 batch
        float4 l01 = ((const float4*)logits)[2 * c + 0];   // rows base, base+1
        float4 l23 = ((const float4*)logits)[2 * c + 1];   // rows base+2, base+3
        int4 lab = ((const int4*)labels)[c];
        int4 bat = ((const int4*)batch)[c];

        float d[4];
        d[0] = l01.y - l01.x;
        d[1] = l01.w - l01.z;
        d[2] = l23.y - l23.x;
        d[3] = l23.w - l23.z;
        int la[4] = { lab.x, lab.y, lab.z, lab.w };
        int ba[4] = { bat.x, bat.y, bat.z, bat.w };

        float p[4];
        #pragma unroll
        for (int k = 0; k < 4; ++k) {
            // nll = softplus(label ? -d : d); weight = 1 or 7
            float x   = la[k] ? -d[k] : d[k];
            float w   = la[k] ? POS_WEIGHT : 1.0f;
            s_wnll += w * softplusf(x);
            s_w    += w;
            p[k] = sigmoidf_(d[k]);
        }

        // internal pairs (base+k, base+k+1), k = 0..2
        #pragma unroll
        for (int k = 0; k < 3; ++k) {
            if (ba[k] == ba[k + 1] && (la[k] | la[k + 1]))
                s_pos += fabsf(p[k + 1] - p[k]);
        }

        // boundary pair (base-1, base) — neighbor cache lines, near-free
        if (base > 0) {
            float2 lp = ((const float2*)logits)[base - 1];  // row base-1
            int lm1 = labels[base - 1];
            int bm1 = batch[base - 1];
            if (bm1 == ba[0] && (lm1 | la[0]))
                s_pos += fabsf(p[0] - sigmoidf_(lp.y - lp.x));
        }
    }

    // generic tail (n % 4 != 0) — unused for N=16M but kept correct
    if ((n & 3) && blockIdx.x == 0 && threadIdx.x == 0) {
        int n4 = nchunks << 2;
        for (int i = n4; i < n; ++i) {
            float d0 = logits[2 * i + 1] - logits[2 * i];
            float x  = labels[i] ? -d0 : d0;
            float w  = labels[i] ? POS_WEIGHT : 1.0f;
            s_wnll += w * softplusf(x);
            s_w    += w;
        }
        int first = (n4 > 0) ? (n4 - 1) : 0;
        for (int i = first; i <= n - 2; ++i) {
            if (batch[i] == batch[i + 1] && (labels[i] | labels[i + 1])) {
                float pa = sigmoidf_(logits[2 * i + 1] - logits[2 * i]);
                float pb = sigmoidf_(logits[2 * i + 3] - logits[2 * i + 2]);
                s_pos += fabsf(pb - pa);
            }
        }
    }

    // wave(64) reduce
    #pragma unroll
    for (int off = 32; off > 0; off >>= 1) {
        s_wnll += __shfl_down(s_wnll, off);
        s_w    += __shfl_down(s_w, off);
        s_pos  += __shfl_down(s_pos, off);
    }

    __shared__ float sa[BLOCK / 64], sb[BLOCK / 64], sc[BLOCK / 64];
    int lane = threadIdx.x & 63;
    int wid  = threadIdx.x >> 6;
    if (lane == 0) { sa[wid] = s_wnll; sb[wid] = s_w; sc[wid] = s_pos; }
    __syncthreads();
    if (threadIdx.x == 0) {
        float ta = 0.0f, tb = 0.0f, tc = 0.0f;
        #pragma unroll
        for (int w = 0; w < BLOCK / 64; ++w) { ta += sa[w]; tb += sb[w]; tc += sc[w]; }
        atomicAdd(&acc[0], ta);
        atomicAdd(&acc[1], tb);
        atomicAdd(&acc[2], tc);
    }
}

__global__ void finalize_kernel(const float* __restrict__ acc, float* __restrict__ out) {
    out[0] = acc[0] / acc[1] + POSITION_WEIGHT * acc[2];
}

extern "C" void kernel_launch(void* const* d_in, const int* in_sizes, int n_in,
                              void* d_out, int out_size, void* d_ws, size_t ws_size,
                              hipStream_t stream) {
    const float* logits = (const float*)d_in[0];
    const int*   labels = (const int*)d_in[1];
    const int*   batch  = (const int*)d_in[2];
    float* out = (float*)d_out;
    float* acc = (float*)d_ws;
    int n = in_sizes[1];   // labels element count == N

    hipMemsetAsync(acc, 0, 3 * sizeof(float), stream);
    pos_loss_kernel<<<NBLOCKS, BLOCK, 0, stream>>>(logits, labels, batch, acc, n);
    finalize_kernel<<<1, 1, 0, stream>>>(acc, out);
}

// Round 2
// 111.694 us; speedup vs baseline: 1.0562x; 1.0562x over previous
//
#include <hip/hip_runtime.h>
#include <math.h>

#define POS_WEIGHT 7.0f
#define POSITION_WEIGHT 0.1f
#define NBLOCKS 2048
#define BLOCK 256

// p = sigmoid(d), using precomputed e = exp(-|d|), t = 1+e
__device__ __forceinline__ float sigmoid_from(float d, float e, float rt) {
    return (d >= 0.0f ? 1.0f : e) * rt;
}

__global__ __launch_bounds__(BLOCK) void pos_loss_kernel(
    const float* __restrict__ logits,   // [n,2]
    const int*   __restrict__ labels,   // [n]
    const int*   __restrict__ batch,    // [n]
    float* __restrict__ acc,            // [3]: sum(w*nll), sum(w), pos_loss
    int n)
{
    const int nchunks = n >> 3;               // 8 elements per chunk
    float s_wnll = 0.0f, s_w = 0.0f, s_pos = 0.0f;

    const int stride = gridDim.x * blockDim.x;
    for (int c = blockIdx.x * blockDim.x + threadIdx.x; c < nchunks; c += stride) {
        const int base = c << 3;

        // 8 logit rows = 4x float4; labels/batch = 2x int4 each
        float4 L0 = ((const float4*)logits)[4 * c + 0];
        float4 L1 = ((const float4*)logits)[4 * c + 1];
        float4 L2 = ((const float4*)logits)[4 * c + 2];
        float4 L3 = ((const float4*)logits)[4 * c + 3];
        int4 lab0 = ((const int4*)labels)[2 * c + 0];
        int4 lab1 = ((const int4*)labels)[2 * c + 1];
        int4 bat0 = ((const int4*)batch)[2 * c + 0];
        int4 bat1 = ((const int4*)batch)[2 * c + 1];

        float d[8] = { L0.y - L0.x, L0.w - L0.z, L1.y - L1.x, L1.w - L1.z,
                       L2.y - L2.x, L2.w - L2.z, L3.y - L3.x, L3.w - L3.z };
        int la[8] = { lab0.x, lab0.y, lab0.z, lab0.w, lab1.x, lab1.y, lab1.z, lab1.w };
        int ba[8] = { bat0.x, bat0.y, bat0.z, bat0.w, bat1.x, bat1.y, bat1.z, bat1.w };

        float p[8];
        #pragma unroll
        for (int k = 0; k < 8; ++k) {
            float dk = d[k];
            float a  = fabsf(dk);
            float e  = __expf(-a);          // shared exp
            float t  = 1.0f + e;
            float Lg = __logf(t);           // softplus(-a) = log(1+e^-a)
            float rt = __builtin_amdgcn_rcpf(t);
            bool dpos = dk >= 0.0f;
            p[k] = sigmoid_from(dk, e, rt);
            // nll = softplus(la ? -d : d) = Lg + (arg>=0 ? a : 0)
            bool xpos = la[k] ? !dpos : dpos;
            float nll = Lg + (xpos ? a : 0.0f);
            float w   = la[k] ? POS_WEIGHT : 1.0f;
            s_wnll = fmaf(w, nll, s_wnll);
            s_w   += w;
        }

        // internal pairs
        #pragma unroll
        for (int k = 0; k < 7; ++k) {
            if (ba[k] == ba[k + 1] && (la[k] | la[k + 1]))
                s_pos += fabsf(p[k + 1] - p[k]);
        }

        // boundary pair (base-1, base): previous chunk is the previous LANE
        // (consecutive lanes own consecutive chunks). Lane 0 falls back to a load.
        float p_prev  = __shfl_up(p[7], 1);
        int   ba_prev = __shfl_up(ba[7], 1);
        int   la_prev = __shfl_up(la[7], 1);
        if ((threadIdx.x & 63) == 0) {
            if (base > 0) {
                float2 lp = ((const float2*)logits)[base - 1];
                la_prev = labels[base - 1];
                ba_prev = batch[base - 1];
                float dd = lp.y - lp.x;
                float aa = fabsf(dd);
                float ee = __expf(-aa);
                float tt = 1.0f + ee;
                p_prev = sigmoid_from(dd, ee, __builtin_amdgcn_rcpf(tt));
            } else {
                ba_prev = -1;   // no predecessor
            }
        }
        if (ba_prev == ba[0] && (la_prev | la[0]))
            s_pos += fabsf(p[0] - p_prev);
    }

    // generic tail (n % 8 != 0) — unused for N=16M but kept correct
    if ((n & 7) && blockIdx.x == 0 && threadIdx.x == 0) {
        int n8 = nchunks << 3;
        for (int i = n8; i < n; ++i) {
            float d0 = logits[2 * i + 1] - logits[2 * i];
            float a  = fabsf(d0);
            float e  = __expf(-a);
            float t  = 1.0f + e;
            float Lg = __logf(t);
            bool dpos = d0 >= 0.0f;
            bool xpos = labels[i] ? !dpos : dpos;
            float w  = labels[i] ? POS_WEIGHT : 1.0f;
            s_wnll += w * (Lg + (xpos ? a : 0.0f));
            s_w    += w;
        }
        int first = (n8 > 0) ? (n8 - 1) : 0;
        for (int i = first; i <= n - 2; ++i) {
            if (batch[i] == batch[i + 1] && (labels[i] | labels[i + 1])) {
                float da = logits[2 * i + 1] - logits[2 * i];
                float db = logits[2 * i + 3] - logits[2 * i + 2];
                float ea = __expf(-fabsf(da)), eb = __expf(-fabsf(db));
                float pa = sigmoid_from(da, ea, __builtin_amdgcn_rcpf(1.0f + ea));
                float pb = sigmoid_from(db, eb, __builtin_amdgcn_rcpf(1.0f + eb));
                s_pos += fabsf(pb - pa);
            }
        }
    }

    // wave(64) reduce
    #pragma unroll
    for (int off = 32; off > 0; off >>= 1) {
        s_wnll += __shfl_down(s_wnll, off);
        s_w    += __shfl_down(s_w, off);
        s_pos  += __shfl_down(s_pos, off);
    }

    __shared__ float sa[BLOCK / 64], sb[BLOCK / 64], sc[BLOCK / 64];
    int lane = threadIdx.x & 63;
    int wid  = threadIdx.x >> 6;
    if (lane == 0) { sa[wid] = s_wnll; sb[wid] = s_w; sc[wid] = s_pos; }
    __syncthreads();
    if (threadIdx.x == 0) {
        float ta = 0.0f, tb = 0.0f, tc = 0.0f;
        #pragma unroll
        for (int w = 0; w < BLOCK / 64; ++w) { ta += sa[w]; tb += sb[w]; tc += sc[w]; }
        atomicAdd(&acc[0], ta);
        atomicAdd(&acc[1], tb);
        atomicAdd(&acc[2], tc);
    }
}

__global__ void finalize_kernel(const float* __restrict__ acc, float* __restrict__ out) {
    out[0] = acc[0] / acc[1] + POSITION_WEIGHT * acc[2];
}

extern "C" void kernel_launch(void* const* d_in, const int* in_sizes, int n_in,
                              void* d_out, int out_size, void* d_ws, size_t ws_size,
                              hipStream_t stream) {
    const float* logits = (const float*)d_in[0];
    const int*   labels = (const int*)d_in[1];
    const int*   batch  = (const int*)d_in[2];
    float* out = (float*)d_out;
    float* acc = (float*)d_ws;
    int n = in_sizes[1];   // labels element count == N

    hipMemsetAsync(acc, 0, 3 * sizeof(float), stream);
    pos_loss_kernel<<<NBLOCKS, BLOCK, 0, stream>>>(logits, labels, batch, acc, n);
    finalize_kernel<<<1, 1, 0, stream>>>(acc, out);
}